// Round 6
// baseline (94.556 us; speedup 1.0000x reference)
//
#include <hip/hip_runtime.h>
#include <stdint.h>

#define KK 5
#define SCALE_F 50000.0f
#define OC 128
#define IC 128
#define HH 56
#define WW 56
#define NB 64
#define HWSZ (HH * WW)          // 3136
#define NTAP 9
#define NWEL (OC * IC * NTAP)   // 147456
#define PW 60                   // padded row stride (u32), 240 B
#define PROWS 58                // padded rows
#define PLANE (PROWS * PW)      // 3480 u32 per (plane, n)
#define PLSTRIDE (NB * PLANE)   // 222720 u32 per plane
#define OCPB 8                  // oc per block (grid.y = 16)
#define WPT 4                   // outputs along w per thread (56 = 14 * 4)

// ---------------------------------------------------------------------------
// Kernel 1: SDP weight gen + binarize + pack.
// One wave per (oc, tap, word64); lane l -> ic = word64*64 + l.
// wpk32 layout: [wd][tap][oc] u32  (wd = ic/32 plane) -> for fixed (wd,tap)
// the 8 consecutive oc words are contiguous => s_load_dwordx8 in bconv.
// ---------------------------------------------------------------------------
__global__ void __launch_bounds__(256) wpack_kernel(
    const float* __restrict__ M, const float* __restrict__ Z,
    const float* __restrict__ rv, uint32_t* __restrict__ wpk32) {
    int gtid = blockIdx.x * blockDim.x + threadIdx.x;
    int lane = gtid & 63;
    int wid  = gtid >> 6;            // 0..2303
    int oc   = wid / 18;
    int r    = wid - oc * 18;
    int tap  = r >> 1;
    int word = r & 1;
    int ic   = word * 64 + lane;
    int idx  = (oc * IC + ic) * NTAP + tap;

    float m  = M[idx];
    float z0 = Z[0 * NWEL + idx];
    float z1 = Z[1 * NWEL + idx];
    float z2 = Z[2 * NWEL + idx];
    float z3 = Z[3 * NWEL + idx];
    float z4 = Z[4 * NWEL + idx];
    float s  = z0 * z0 + z1 * z1 + z2 * z2 + z3 * z3 + z4 * z4;
    float A  = m * m + s * (1.0f / SCALE_F);
    float inv = 1.0f / sqrtf(A);
    float w = rv[0] * (z0 * inv);
    w += rv[1] * (z1 * inv);
    w += rv[2] * (z2 * inv);
    w += rv[3] * (z3 * inv);
    w += rv[4] * (z4 * inv);
    w += m * inv;

    unsigned long long b = __ballot(w > 0.0f);
    if (lane == 0) {
        wpk32[((word * 2 + 0) * NTAP + tap) * OC + oc] = (uint32_t)b;
        wpk32[((word * 2 + 1) * NTAP + tap) * OC + oc] = (uint32_t)(b >> 32);
    }
}

// ---------------------------------------------------------------------------
// Kernel 2: binarize + pack activations into 4 ZERO-PADDED u32 planes.
// Plane wd holds ic wd*32..wd*32+31. grid = (784, 4); blockIdx.y = plane.
// ---------------------------------------------------------------------------
__global__ void __launch_bounds__(256) apack_kernel(
    const float* __restrict__ x, uint32_t* __restrict__ apk32) {
    int q  = blockIdx.x * blockDim.x + threadIdx.x;   // 0..200703
    int wd = blockIdx.y;                              // 0..3
    int n  = q / HWSZ;
    int hw = q - n * HWSZ;
    int h  = hw / WW;
    int w  = hw - h * WW;
    const float* xp = x + (size_t)n * IC * HWSZ + (size_t)wd * 32 * HWSZ + hw;

    uint32_t b = 0;
#pragma unroll
    for (int c = 0; c < 32; ++c)
        b |= (uint32_t)(xp[(size_t)c * HWSZ] > 0.0f) << c;

    apk32[(size_t)wd * PLSTRIDE + (size_t)n * PLANE + (size_t)(h + 1) * PW + (w + 1)] = b;
}

// ---------------------------------------------------------------------------
// Kernel 3: XNOR-popcount conv. grid = (196, 16), 256 threads.
// Thread -> (n, h, 4-wide w strip) x OCPB=8 output channels.
// Rolled (r, wd) loops: live set = cnt[32] + T[6] + addr (~52 VGPR).
// Tap loads amortized over 32 outputs (2.25 u32/output, 4x less L1 traffic
// than R5). Weights: uniform s_load_dwordx8 per (wd,tap) -> scalar pipe.
// ---------------------------------------------------------------------------
__global__ void __launch_bounds__(256, 4) bconv_kernel(
    const uint32_t* __restrict__ apk32, const uint32_t* __restrict__ wpk32,
    const float* __restrict__ alpha, float* __restrict__ out) {
    __shared__ int adj[OCPB][9];               // border-class correction
    __shared__ float alf[OCPB];

    int tx  = threadIdx.x;
    int oc0 = blockIdx.y * OCPB;

    if (tx < OCPB) alf[tx] = alpha[oc0 + tx];
    if (tx < OCPB * 9) {
        int ocl = tx / 9, cls = tx % 9;
        int rc = cls / 3, cc = cls % 3;
        int nv = ((rc == 1) ? 3 : 2) * ((cc == 1) ? 3 : 2);
        int s = 0;
#pragma unroll
        for (int t = 0; t < NTAP; ++t) {
            int i = t / 3, j = t % 3;
            bool invld = (rc == 0 && i == 0) || (rc == 2 && i == 2) ||
                         (cc == 0 && j == 0) || (cc == 2 && j == 2);
            if (invld) {
#pragma unroll
                for (int wd = 0; wd < 4; ++wd)
                    s += __popc(wpk32[(wd * NTAP + t) * OC + oc0 + ocl]);
            }
        }
        adj[ocl][cls] = 128 * nv + 2 * s;
    }
    __syncthreads();

    int t  = blockIdx.x * blockDim.x + tx;     // 0..50175
    int sw = t % 14;
    int h  = (t / 14) % HH;
    int n  = t / (14 * HH);
    int w0 = sw * WPT;                         // 0,4,...,52

    // padded base: rows h..h+2, cols w0..w0+5 (16B-aligned)
    const uint32_t* ap = apk32 + (size_t)n * PLANE + (size_t)h * PW + w0;

    int cnt[WPT * OCPB] = {0};                 // 32 accumulators
#pragma unroll 1
    for (int r = 0; r < 3; ++r) {
#pragma unroll 1
        for (int wd = 0; wd < 4; ++wd) {
            const uint32_t* p = ap + (size_t)wd * PLSTRIDE + (size_t)r * PW;
            uint32_t T[6];
#pragma unroll
            for (int c = 0; c < 6; ++c) T[c] = p[c];
            const uint32_t* wrow = wpk32 + (wd * NTAP + r * 3) * OC + oc0;
#pragma unroll
            for (int j = 0; j < 3; ++j) {
#pragma unroll
                for (int ocl = 0; ocl < OCPB; ++ocl) {
                    uint32_t wv = wrow[j * OC + ocl];   // uniform -> s_load x8
#pragma unroll
                    for (int o = 0; o < WPT; ++o)
                        cnt[o * OCPB + ocl] += __popc(T[j + o] ^ wv);
                }
            }
        }
    }

    int rcls = (h == 0) ? 0 : ((h == HH - 1) ? 6 : 3);
    int clsL = rcls + ((w0 == 0) ? 0 : 1);
    int clsI = rcls + 1;
    int clsR = rcls + ((w0 == WW - WPT) ? 2 : 1);
    float* op = out + ((size_t)n * OC + oc0) * HWSZ + h * WW + w0;
#pragma unroll
    for (int ocl = 0; ocl < OCPB; ++ocl) {
        float a = alf[ocl];
        float4 v;
        v.x = (float)(adj[ocl][clsL] - 2 * cnt[0 * OCPB + ocl]) * a;
        v.y = (float)(adj[ocl][clsI] - 2 * cnt[1 * OCPB + ocl]) * a;
        v.z = (float)(adj[ocl][clsI] - 2 * cnt[2 * OCPB + ocl]) * a;
        v.w = (float)(adj[ocl][clsR] - 2 * cnt[3 * OCPB + ocl]) * a;
        *(float4*)(op + (size_t)ocl * HWSZ) = v;
    }
}

extern "C" void kernel_launch(void* const* d_in, const int* in_sizes, int n_in,
                              void* d_out, int out_size, void* d_ws, size_t ws_size,
                              hipStream_t stream) {
    const float* x     = (const float*)d_in[0];
    const float* M     = (const float*)d_in[1];
    const float* Z     = (const float*)d_in[2];
    const float* Alpha = (const float*)d_in[3];
    const float* rv    = (const float*)d_in[4];
    float* out = (float*)d_out;

    uint32_t* wpk32 = (uint32_t*)d_ws;                        // 18,432 B
    uint32_t* apk32 = (uint32_t*)((char*)d_ws + 32768);       // 4*222720*4 B

    // zero the padded activation planes (borders must be 0 every call)
    hipMemsetAsync(apk32, 0, (size_t)4 * PLSTRIDE * 4, stream);

    wpack_kernel<<<NWEL / 256, 256, 0, stream>>>(M, Z, rv, wpk32);
    apack_kernel<<<dim3((NB * HWSZ) / 256, 4), 256, 0, stream>>>(x, apk32);
    bconv_kernel<<<dim3((NB * HH * 14) / 256, OC / OCPB), 256, 0, stream>>>(
        apk32, wpk32, Alpha, out);
}